// Round 10
// baseline (398.479 us; speedup 1.0000x reference)
//
#include <hip/hip_runtime.h>
#include <hip/hip_bf16.h>
#include <math.h>

namespace {

constexpr int B_ = 2, P_ = 12, N_ = 170, DM_ = 64, H_ = 8, DK_ = 8, DH_ = 32, DF_ = 256;
constexpr int T_ = B_ * P_ * N_;        // 4080 tokens
constexpr float SQRT_DK = 2.8284271247461903f;

constexpr int NG_ = 12;                 // 192 output cols / 16
constexpr int NC_ = 66;                 // 2112 K / 32
constexpr int WFRAG_G = NG_ * NC_ * 64 * 8;   // shorts per graph = 405504

typedef __attribute__((ext_vector_type(4))) short short4v;
typedef __attribute__((ext_vector_type(8))) short short8v;
typedef __attribute__((ext_vector_type(4))) float float4v;

// float -> bf16 bits, round-to-nearest-even
__device__ __forceinline__ unsigned short f2bf(float x) {
    union { float f; unsigned int u; } c; c.f = x;
    unsigned int r = (c.u + 0x7FFFu + ((c.u >> 16) & 1u)) >> 16;
    return (unsigned short)r;
}

// ---------- meta hidden (x3 batched): hr = relu(c_x @ w1 + b1)  [T_,32] ----------
__global__ void k_hr3(const float* __restrict__ c_x,
                      const float* __restrict__ w1a, const float* __restrict__ b1a,
                      const float* __restrict__ w1b, const float* __restrict__ b1b,
                      const float* __restrict__ w1c, const float* __restrict__ b1c,
                      float* __restrict__ hra, float* __restrict__ hrb,
                      float* __restrict__ hrc) {
    int z = blockIdx.y;
    const float* w1 = z == 0 ? w1a : (z == 1 ? w1b : w1c);
    const float* b1 = z == 0 ? b1a : (z == 1 ? b1b : b1c);
    float* hr = z == 0 ? hra : (z == 1 ? hrb : hrc);
    int idx = blockIdx.x * 256 + threadIdx.x;          // t*32 + j
    if (idx >= T_ * DH_) return;
    int t = idx / DH_, j = idx % DH_;
    float acc = b1[j];
    const float* cx = c_x + t * DM_;
    #pragma unroll
    for (int d = 0; d < DM_; ++d) acc += cx[d] * w1[d * DH_ + j];
    hr[idx] = fmaxf(acc, 0.f);
}

// ---------- one-time w2/b2 -> bf16 B-fragment-linear permute ----------
__global__ void k_wconv(const float* __restrict__ w2a, const float* __restrict__ b2a,
                        const float* __restrict__ w2b, const float* __restrict__ b2b,
                        const float* __restrict__ w2c, const float* __restrict__ b2c,
                        unsigned short* __restrict__ Wfrag) {
    int idx = blockIdx.x * 256 + threadIdx.x;   // ((g*12+ng)*66+c)*64 + lane
    if (idx >= 3 * NG_ * NC_ * 64) return;
    int lane = idx & 63;
    int c = (idx >> 6) % NC_;
    int ng = (idx >> 6) / NC_ % NG_;
    int g = idx / (64 * NC_ * NG_);
    const float* w2 = g == 0 ? w2a : (g == 1 ? w2b : w2c);
    const float* b2 = g == 0 ? b2a : (g == 1 ? b2b : b2c);
    int m = ng * 16 + (lane & 15);
    int u = c >> 1;                              // jh
    int d0 = (c & 1) * 32 + (lane >> 4) * 8;
    const float* src = (u < DH_) ? (w2 + u * 12288 + m * 64 + d0) : (b2 + m * 64 + d0);
    short8v o;
    #pragma unroll
    for (int j = 0; j < 8; ++j) o[j] = (short)f2bf(src[j]);
    *(short8v*)(Wfrag + (size_t)idx * 8) = o;
}

// ---------- meta+mhlin GEMM v2: no LDS, no barriers ----------
__global__ __launch_bounds__(256) void k_meta_gemm2(
    const float* __restrict__ hr0, const float* __restrict__ hr1,
    const float* __restrict__ xin,
    const unsigned short* __restrict__ Wf0, const unsigned short* __restrict__ Wf1,
    float* __restrict__ out0, float* __restrict__ out1) {
    const int bz = blockIdx.z;
    const float* hr = bz ? hr1 : hr0;
    const unsigned short* Wf = bz ? Wf1 : Wf0;
    float* out = bz ? out1 : out0;

    const int tid = threadIdx.x;
    const int wv = tid >> 6, lane = tid & 63;
    const int l15 = lane & 15, quad = lane >> 4;
    const int g16 = blockIdx.x * 4 + wv;
    if (g16 >= 255) return;
    const int t = g16 * 16 + l15;
    const int nb = blockIdx.y;                   // 0..2

    const float* xp = xin + t * 64 + quad * 8;
    float4v xa = *(const float4v*)(xp);
    float4v xb = *(const float4v*)(xp + 4);
    float4v xc = *(const float4v*)(xp + 32);
    float4v xd = *(const float4v*)(xp + 36);
    float xr[16] = {xa.x, xa.y, xa.z, xa.w, xb.x, xb.y, xb.z, xb.w,
                    xc.x, xc.y, xc.z, xc.w, xd.x, xd.y, xd.z, xd.w};

    const float* hrp = hr + t * 32;
    float4v acc[4] = {{0.f,0.f,0.f,0.f},{0.f,0.f,0.f,0.f},
                      {0.f,0.f,0.f,0.f},{0.f,0.f,0.f,0.f}};

    const unsigned short* wb = Wf + ((size_t)(nb * 4) * NC_ * 64 + lane) * 8;
    const size_t qstride = (size_t)NC_ * 64 * 8;
    const size_t cstride = 64 * 8;

    for (int u = 0; u < 33; ++u) {
        float hrv = (u < DH_) ? hrp[u] : 1.0f;
        short8v a0, a1;
        #pragma unroll
        for (int j = 0; j < 8; ++j) {
            a0[j] = (short)f2bf(hrv * xr[j]);
            a1[j] = (short)f2bf(hrv * xr[8 + j]);
        }
        const unsigned short* wc = wb + (size_t)(2 * u) * cstride;
        #pragma unroll
        for (int q = 0; q < 4; ++q) {
            short8v b0 = *(const short8v*)(wc + q * qstride);
            short8v b1 = *(const short8v*)(wc + q * qstride + cstride);
            acc[q] = __builtin_amdgcn_mfma_f32_16x16x32_bf16(a0, b0, acc[q], 0, 0, 0);
            acc[q] = __builtin_amdgcn_mfma_f32_16x16x32_bf16(a1, b1, acc[q], 0, 0, 0);
        }
    }

    #pragma unroll
    for (int q = 0; q < 4; ++q) {
        #pragma unroll
        for (int r = 0; r < 4; ++r) {
            int tt = g16 * 16 + quad * 4 + r;
            out[tt * 192 + nb * 64 + q * 16 + l15] = acc[q][r];
        }
    }
}

// ---------- retnet temporal retention: block per (b,n), 256 thr ----------
__global__ __launch_bounds__(256) void k_retnet(const float* __restrict__ qkv,
                                                const float* __restrict__ Dm,
                                                float* __restrict__ att) {
    const int bn = blockIdx.x;           // b*N + n
    const int b = bn / N_, n = bn % N_;
    __shared__ float S[12][192];
    __shared__ float Ds[8 * 145];
    const int tid = threadIdx.x;
    for (int e = tid; e < 12 * 192; e += 256) {
        int p = e / 192, c = e % 192;
        S[p][c] = qkv[((size_t)((b * P_ + p) * N_ + n)) * 192 + c];
    }
    for (int e = tid; e < 1152; e += 256) {
        Ds[(e / 144) * 145 + (e % 144)] = Dm[e];
    }
    __syncthreads();
    const int qq = tid >> 6;
    const int lane = tid & 63;
    const int h = lane >> 3, k = lane & 7;
    for (int q = qq; q < P_; q += 4) {
        float Qv = S[q][h * 8 + k];
        float r[P_];
        float rsum = 0.f;
        #pragma unroll
        for (int p = 0; p < P_; ++p) {
            float prod = Qv * S[p][64 + h * 8 + k];
            prod += __shfl_xor(prod, 1, 64);
            prod += __shfl_xor(prod, 2, 64);
            prod += __shfl_xor(prod, 4, 64);
            float s = (prod / SQRT_DK) * Ds[h * 145 + q * 12 + p];
            r[p] = s; rsum += s;
        }
        float rs = fmaxf(fabsf(rsum), 1.0f);
        float acc = 0.f;
        #pragma unroll
        for (int p = 0; p < P_; ++p) acc += (r[p] / rs) * S[p][128 + h * 8 + k];
        att[((size_t)((b * P_ + q) * N_ + n)) * 64 + lane] = acc;
    }
}

// ---------- temporal enc-dec attention ----------
__global__ __launch_bounds__(256) void k_temporal(const float* __restrict__ qkv,
                                                  float* __restrict__ att) {
    const int bn = blockIdx.x;
    const int b = bn / N_, n = bn % N_;
    __shared__ float S[12][192];
    const int tid = threadIdx.x;
    for (int e = tid; e < 12 * 192; e += 256) {
        int p = e / 192, c = e % 192;
        S[p][c] = qkv[((size_t)((b * P_ + p) * N_ + n)) * 192 + c];
    }
    __syncthreads();
    const int qq = tid >> 6;
    const int lane = tid & 63;
    const int h = lane >> 3, k = lane & 7;
    for (int q = qq; q < P_; q += 4) {
        float Qv = S[q][h * 8 + k];
        float s[P_];
        float mx = -1e30f;
        #pragma unroll
        for (int p = 0; p < P_; ++p) {
            float prod = Qv * S[p][64 + h * 8 + k];
            prod += __shfl_xor(prod, 1, 64);
            prod += __shfl_xor(prod, 2, 64);
            prod += __shfl_xor(prod, 4, 64);
            float v = prod / SQRT_DK;
            s[p] = v; mx = fmaxf(mx, v);
        }
        float den = 0.f, acc = 0.f;
        #pragma unroll
        for (int p = 0; p < P_; ++p) {
            float e = expf(s[p] - mx);
            den += e;
            acc += e * S[p][128 + h * 8 + k];
        }
        att[((size_t)((b * P_ + q) * N_ + n)) * 64 + lane] = acc / den;
    }
}

// ---------- spatial attention v4: block (bp, h, g*4+ichunk); lanes span j ----------
__global__ __launch_bounds__(256) void k_spatial4(
    const float* __restrict__ qkvA, const float* __restrict__ qkvB,
    const float* __restrict__ Tm, const float* __restrict__ Am,
    float* __restrict__ attA, float* __restrict__ attB) {
    const int bp = blockIdx.x;          // 0..23
    const int h = blockIdx.y;           // 0..7
    const int g = blockIdx.z >> 2;      // 0,1
    const int ic = blockIdx.z & 3;      // i-chunk
    const float* qkv = g ? qkvB : qkvA;
    float* att = g ? attB : attA;

    __shared__ float sKt[8][192];       // [k][j] transposed
    __shared__ float sV[192][8];        // [j][k]
    __shared__ float sW[4][192];

    const int tid = threadIdx.x;
    for (int e = tid; e < 384; e += 256) {
        int j = e >> 1, kh = (e & 1) * 4;
        float4v k4 = {0.f, 0.f, 0.f, 0.f}, v4 = k4;
        if (j < N_) {
            const float* row = qkv + (size_t)(bp * N_ + j) * 192 + h * 8 + kh;
            k4 = *(const float4v*)(row + 64);
            v4 = *(const float4v*)(row + 128);
        }
        sKt[kh + 0][j] = k4.x;
        sKt[kh + 1][j] = k4.y;
        sKt[kh + 2][j] = k4.z;
        sKt[kh + 3][j] = k4.w;
        *(float4v*)&sV[j][kh] = v4;
    }
    __syncthreads();

    const int wv = tid >> 6;
    const int lane = tid & 63;
    const int j8 = lane >> 3, kk = lane & 7;

    const int i0 = ic * 43;
    const int i1 = (i0 + 43 < N_) ? (i0 + 43) : N_;

    for (int i = i0 + wv; i < i1; i += 4) {
        const float* qrow = qkv + (size_t)(bp * N_ + i) * 192 + h * 8;
        float4v qa = *(const float4v*)qrow;       // uniform: broadcast
        float4v qb = *(const float4v*)(qrow + 4);
        float Qi[8] = {qa.x, qa.y, qa.z, qa.w, qb.x, qb.y, qb.z, qb.w};
        const float* Trow = g ? (Am + (size_t)(bp * N_ + i) * N_) : (Tm + (size_t)i * N_);

        float sloc[3], tloc[3];
        float mx = -1e30f;
        #pragma unroll
        for (int c = 0; c < 3; ++c) {
            int j = c * 64 + lane;
            float tv = 0.f, s = -1e30f;
            if (j < N_) {
                tv = Trow[j];
                if (tv != 0.f) {
                    float dot = 0.f;
                    #pragma unroll
                    for (int k = 0; k < 8; ++k) dot += Qi[k] * sKt[k][j];
                    s = dot / SQRT_DK;
                } else {
                    s = 0.f;   // masked entries are exact zeros and DO enter the max
                }
            }
            sloc[c] = s; tloc[c] = tv;
            mx = fmaxf(mx, s);
        }
        #pragma unroll
        for (int off = 1; off < 64; off <<= 1) mx = fmaxf(mx, __shfl_xor(mx, off, 64));

        float den = 0.f;
        #pragma unroll
        for (int c = 0; c < 3; ++c) {
            float s = sloc[c];
            float e = (s != 0.f) ? expf(s - mx) : 0.f;  // j>=N_: s=-1e30 -> e==0
            den += e;
            sW[wv][c * 64 + lane] = e * tloc[c];
        }
        #pragma unroll
        for (int off = 1; off < 64; off <<= 1) den += __shfl_xor(den, off, 64);

        float acc = 0.f;
        #pragma unroll 4
        for (int j = j8; j < 192; j += 8) acc += sW[wv][j] * sV[j][kk];
        acc += __shfl_xor(acc, 8, 64);
        acc += __shfl_xor(acc, 16, 64);
        acc += __shfl_xor(acc, 32, 64);
        if (lane < 8)
            att[(size_t)(bp * N_ + i) * 64 + h * 8 + lane] = acc / (den + 1e-5f);
    }
}

__device__ __forceinline__ float ln_out(float r, int dm, const float* g, const float* b) {
    float m = r, m2 = r * r;
    #pragma unroll
    for (int off = 32; off; off >>= 1) { m += __shfl_xor(m, off, 64); m2 += __shfl_xor(m2, off, 64); }
    m *= (1.f / 64.f); m2 *= (1.f / 64.f);
    float var = m2 - m * m;
    return (r - m) * rsqrtf(var + 1e-5f) * g[dm] + b[dm];
}

// gdc for ONE token from LDS-resident weights (16 accum registers)
__device__ __forceinline__ float gdc8_lds(const float* dv, const float* W1s,
                                          const float* W2s, int dm) {
    float a[8], s[8];
    #pragma unroll
    for (int g = 0; g < 8; ++g) { a[g] = 0.f; s[g] = 0.f; }
    for (int g = 0; g < 8; ++g) {
        #pragma unroll
        for (int c = 0; c < 8; ++c) {
            float d = dv[g * 8 + c];
            int idx = (g * 8 + c) * 64 + dm;
            a[g] += d * W1s[idx];
            s[g] += d * W2s[idx];
        }
    }
    float mx = fmaxf(s[0], 0.f);
    #pragma unroll
    for (int g = 1; g < 8; ++g) mx = fmaxf(mx, fmaxf(s[g], 0.f));
    float den = 0.f, o = 0.f;
    #pragma unroll
    for (int g = 0; g < 8; ++g) {
        float e = expf(fmaxf(s[g], 0.f) - mx);
        den += e; o += a[g] * e;
    }
    return o / den;
}

// ---------- gsl v4: 8 tokens/block, ALL weights LDS-staged (64 KB, 1 phase) ----------
__global__ __launch_bounds__(256) void k_gsl4(const float* __restrict__ att,
    const float* __restrict__ xin,
    const float* __restrict__ W1, const float* __restrict__ W2,
    const float* __restrict__ wg, const float* __restrict__ bg,
    const float* __restrict__ wo, const float* __restrict__ bo,
    const float* __restrict__ lng, const float* __restrict__ lnb,
    float* __restrict__ xout) {
    __shared__ float Wbuf[16384];    // [0:4096) W1, [4096) W2, [8192) wg, [12288) wo
    __shared__ float dv[8][64], xv[8][64], sw[8][64];
    const int tid = threadIdx.x;
    const int t0 = blockIdx.x * 8;
    for (int e = tid; e < 1024; e += 256) {
        *(float4v*)&Wbuf[e * 4]         = *(const float4v*)&W1[e * 4];
        *(float4v*)&Wbuf[4096 + e * 4]  = *(const float4v*)&W2[e * 4];
        *(float4v*)&Wbuf[8192 + e * 4]  = *(const float4v*)&wg[e * 4];
        *(float4v*)&Wbuf[12288 + e * 4] = *(const float4v*)&wo[e * 4];
    }
    for (int e = tid; e < 512; e += 256) {
        dv[e >> 6][e & 63] = att[(size_t)(t0 + (e >> 6)) * 64 + (e & 63)];
        xv[e >> 6][e & 63] = xin[(size_t)(t0 + (e >> 6)) * 64 + (e & 63)];
    }
    __syncthreads();
    const int wv = tid >> 6, dm = tid & 63;
    const float bgv = bg[dm], bov = bo[dm];
    for (int it = 0; it < 2; ++it) {
        const int r = wv * 2 + it;
        float o = gdc8_lds(dv[r], Wbuf, Wbuf + 4096, dm);
        float hg = bgv;
        for (int d = 0; d < 64; ++d) hg += xv[r][d] * Wbuf[8192 + d * 64 + dm];
        hg *= o;
        sw[r][dm] = hg / (1.f + expf(-hg));      // wave-local row
        float ov = bov;
        for (int d = 0; d < 64; ++d) ov += sw[r][d] * Wbuf[12288 + d * 64 + dm];
        float rr = ov + xv[r][dm];
        xout[(size_t)(t0 + r) * 64 + dm] = ln_out(rr, dm, lng, lnb);
    }
}

// ---------- spatial tail v4: 8 tokens/block, 3-phase 64 KB weight staging ----------
__global__ __launch_bounds__(256) void k_spatial_fuse4(
    const float* __restrict__ att0, const float* __restrict__ att1,
    const float* __restrict__ x1,
    const float* __restrict__ gs0_W1, const float* __restrict__ gs0_W2,
    const float* __restrict__ gs1_W1, const float* __restrict__ gs1_W2,
    const float* __restrict__ g2_W1, const float* __restrict__ g2_W2,
    const float* __restrict__ wg, const float* __restrict__ bg,
    const float* __restrict__ wo, const float* __restrict__ bo,
    const float* __restrict__ lng, const float* __restrict__ lnb,
    float* __restrict__ xout) {
    __shared__ float Wbuf[16384];
    __shared__ float d0s[8][64], d1s[8][64], x1s[8][64];
    __shared__ float o0s[8][64], o1s[8][64], sws[8][64];
    const int tid = threadIdx.x;
    const int t0 = blockIdx.x * 8;
    // phase A: gdc weights (4 x 16 KB)
    for (int e = tid; e < 1024; e += 256) {
        *(float4v*)&Wbuf[e * 4]         = *(const float4v*)&gs0_W1[e * 4];
        *(float4v*)&Wbuf[4096 + e * 4]  = *(const float4v*)&gs0_W2[e * 4];
        *(float4v*)&Wbuf[8192 + e * 4]  = *(const float4v*)&gs1_W1[e * 4];
        *(float4v*)&Wbuf[12288 + e * 4] = *(const float4v*)&gs1_W2[e * 4];
    }
    for (int e = tid; e < 512; e += 256) {
        d0s[e >> 6][e & 63] = att0[(size_t)(t0 + (e >> 6)) * 64 + (e & 63)];
        d1s[e >> 6][e & 63] = att1[(size_t)(t0 + (e >> 6)) * 64 + (e & 63)];
        x1s[e >> 6][e & 63] = x1[(size_t)(t0 + (e >> 6)) * 64 + (e & 63)];
    }
    __syncthreads();
    const int wv = tid >> 6, dm = tid & 63;
    for (int it = 0; it < 2; ++it) {
        const int r = wv * 2 + it;
        o0s[r][dm] = gdc8_lds(d0s[r], Wbuf, Wbuf + 4096, dm);
        o1s[r][dm] = gdc8_lds(d1s[r], Wbuf + 8192, Wbuf + 12288, dm);
    }
    __syncthreads();
    // phase B: g2 weights (2 x 32 KB)
    for (int e = tid; e < 2048; e += 256) {
        *(float4v*)&Wbuf[e * 4]        = *(const float4v*)&g2_W1[e * 4];
        *(float4v*)&Wbuf[8192 + e * 4] = *(const float4v*)&g2_W2[e * 4];
    }
    __syncthreads();
    float og[2];
    for (int it = 0; it < 2; ++it) {
        const int r = wv * 2 + it;
        float a0 = 0.f, s0 = 0.f, a1 = 0.f, s1 = 0.f;
        for (int c = 0; c < 64; ++c) {
            float v0 = o0s[r][c], v1 = o1s[r][c];
            a0 += v0 * Wbuf[c * 64 + dm];
            s0 += v0 * Wbuf[8192 + c * 64 + dm];
            a1 += v1 * Wbuf[4096 + c * 64 + dm];
            s1 += v1 * Wbuf[12288 + c * 64 + dm];
        }
        s0 = fmaxf(s0, 0.f); s1 = fmaxf(s1, 0.f);
        float mx = fmaxf(s0, s1);
        float e0 = expf(s0 - mx), e1 = expf(s1 - mx);
        og[it] = (a0 * e0 + a1 * e1) / (e0 + e1);
    }
    __syncthreads();
    // phase C: swish weights (2 x 16 KB)
    for (int e = tid; e < 1024; e += 256) {
        *(float4v*)&Wbuf[e * 4]        = *(const float4v*)&wg[e * 4];
        *(float4v*)&Wbuf[4096 + e * 4] = *(const float4v*)&wo[e * 4];
    }
    __syncthreads();
    const float bgv = bg[dm], bov = bo[dm];
    for (int it = 0; it < 2; ++it) {
        const int r = wv * 2 + it;
        float hg = bgv;
        for (int d = 0; d < 64; ++d) hg += x1s[r][d] * Wbuf[d * 64 + dm];
        hg *= og[it];
        sws[r][dm] = hg / (1.f + expf(-hg));     // wave-local row
        float ov = bov;
        for (int d = 0; d < 64; ++d) ov += sws[r][d] * Wbuf[4096 + d * 64 + dm];
        float rr = ov + x1s[r][dm];
        xout[(size_t)(t0 + r) * 64 + dm] = ln_out(rr, dm, lng, lnb);
    }
}

// ---------- qkv projection v4: 8 tokens/block, 48 KB weights in LDS ----------
__global__ __launch_bounds__(256) void k_qkvproj4(const float* __restrict__ x2,
    const float* __restrict__ enc,
    const float* __restrict__ wq, const float* __restrict__ wk,
    const float* __restrict__ wvp,
    float* __restrict__ qkv) {
    __shared__ float Wbuf[12288];    // [0:4096) wq, [4096) wk, [8192) wv
    __shared__ float xs[8][64], es[8][64];
    const int tid = threadIdx.x;
    const int t0 = blockIdx.x * 8;
    for (int e = tid; e < 1024; e += 256) {
        *(float4v*)&Wbuf[e * 4]        = *(const float4v*)&wq[e * 4];
        *(float4v*)&Wbuf[4096 + e * 4] = *(const float4v*)&wk[e * 4];
        *(float4v*)&Wbuf[8192 + e * 4] = *(const float4v*)&wvp[e * 4];
    }
    for (int e = tid; e < 512; e += 256) {
        xs[e >> 6][e & 63] = x2[(size_t)(t0 + (e >> 6)) * 64 + (e & 63)];
        es[e >> 6][e & 63] = enc[(size_t)(t0 + (e >> 6)) * 64 + (e & 63)];
    }
    __syncthreads();
    const int wv = tid >> 6, dm = tid & 63;
    for (int it = 0; it < 2; ++it) {
        const int r = wv * 2 + it;
        float aq = 0.f, ak = 0.f, av = 0.f;
        for (int d = 0; d < 64; ++d) {
            float xvv = xs[r][d], evv = es[r][d];
            aq += xvv * Wbuf[d * 64 + dm];
            ak += evv * Wbuf[4096 + d * 64 + dm];
            av += evv * Wbuf[8192 + d * 64 + dm];
        }
        size_t tg = t0 + r;
        qkv[tg * 192 + dm] = aq;
        qkv[tg * 192 + 64 + dm] = ak;
        qkv[tg * 192 + 128 + dm] = av;
    }
}

// ---------- FFN v4: 8 tokens/block, 2-phase 64 KB weight staging ----------
__global__ __launch_bounds__(256) void k_ffn4(const float* __restrict__ x3,
    const float* __restrict__ w1, const float* __restrict__ b1,
    const float* __restrict__ w2, const float* __restrict__ b2,
    const float* __restrict__ lng, const float* __restrict__ lnb,
    float* __restrict__ out) {
    __shared__ float Wbuf[16384];
    __shared__ float hv[8][256];
    __shared__ float xs[8][64];
    const int tid = threadIdx.x;
    const int t0 = blockIdx.x * 8;
    // phase A: w1 (64 KB)
    for (int e = tid; e < 4096; e += 256)
        *(float4v*)&Wbuf[e * 4] = *(const float4v*)&w1[e * 4];
    for (int e = tid; e < 512; e += 256)
        xs[e >> 6][e & 63] = x3[(size_t)(t0 + (e >> 6)) * 64 + (e & 63)];
    __syncthreads();
    const int wv = tid >> 6, dm = tid & 63;
    for (int it = 0; it < 2; ++it) {
        const int r = wv * 2 + it;
        #pragma unroll
        for (int e = 0; e < 4; ++e) {
            int j = e * 64 + dm;
            float a = b1[j];
            for (int d = 0; d < 64; ++d) a += xs[r][d] * Wbuf[d * 256 + j];
            hv[r][j] = fmaxf(a, 0.f);
        }
    }
    __syncthreads();
    // phase B: w2 (64 KB)
    for (int e = tid; e < 4096; e += 256)
        *(float4v*)&Wbuf[e * 4] = *(const float4v*)&w2[e * 4];
    __syncthreads();
    const float b2v = b2[dm];
    for (int it = 0; it < 2; ++it) {
        const int r = wv * 2 + it;
        float a = b2v;
        for (int j = 0; j < 256; ++j) a += hv[r][j] * Wbuf[j * 64 + dm];
        float rr = a + xs[r][dm];
        out[(size_t)(t0 + r) * 64 + dm] = ln_out(rr, dm, lng, lnb);
    }
}

} // namespace

extern "C" void kernel_launch(void* const* d_in, const int* in_sizes, int n_in,
                              void* d_out, int out_size, void* d_ws, size_t ws_size,
                              hipStream_t stream) {
    (void)in_sizes; (void)n_in; (void)out_size; (void)ws_size;
    const float* x    = (const float*)d_in[0];
    const float* c_x  = (const float*)d_in[1];
    const float* enc  = (const float*)d_in[2];
    const float* Tm   = (const float*)d_in[3];
    const float* Am   = (const float*)d_in[4];
    const float* Dm   = (const float*)d_in[5];
    const float* mr_w1 = (const float*)d_in[6];
    const float* mr_b1 = (const float*)d_in[7];
    const float* mr_w2 = (const float*)d_in[8];
    const float* mr_b2 = (const float*)d_in[9];
    const float* ms0_w1 = (const float*)d_in[10];
    const float* ms0_b1 = (const float*)d_in[11];
    const float* ms0_w2 = (const float*)d_in[12];
    const float* ms0_b2 = (const float*)d_in[13];
    const float* ms1_w1 = (const float*)d_in[14];
    const float* ms1_b1 = (const float*)d_in[15];
    const float* ms1_w2 = (const float*)d_in[16];
    const float* ms1_b2 = (const float*)d_in[17];
    const float* gr_W1 = (const float*)d_in[18];
    const float* gr_W2 = (const float*)d_in[19];
    const float* gs0_W1 = (const float*)d_in[20];
    const float* gs0_W2 = (const float*)d_in[21];
    const float* gs1_W1 = (const float*)d_in[22];
    const float* gs1_W2 = (const float*)d_in[23];
    const float* g2_W1 = (const float*)d_in[24];
    const float* g2_W2 = (const float*)d_in[25];
    const float* ge_W1 = (const float*)d_in[26];
    const float* ge_W2 = (const float*)d_in[27];
    const float* swr_wg = (const float*)d_in[28];
    const float* swr_bg = (const float*)d_in[29];
    const float* swr_wo = (const float*)d_in[30];
    const float* swr_bo = (const float*)d_in[31];
    const float* sws_wg = (const float*)d_in[32];
    const float* sws_bg = (const float*)d_in[33];
    const float* sws_wo = (const float*)d_in[34];
    const float* sws_bo = (const float*)d_in[35];
    const float* swe_wg = (const float*)d_in[36];
    const float* swe_bg = (const float*)d_in[37];
    const float* swe_wo = (const float*)d_in[38];
    const float* swe_bo = (const float*)d_in[39];
    const float* lnr_g = (const float*)d_in[40];
    const float* lnr_b = (const float*)d_in[41];
    const float* lns_g = (const float*)d_in[42];
    const float* lns_b = (const float*)d_in[43];
    const float* lne_g = (const float*)d_in[44];
    const float* lne_b = (const float*)d_in[45];
    const float* lnf_g = (const float*)d_in[46];
    const float* lnf_b = (const float*)d_in[47];
    const float* wq = (const float*)d_in[48];
    const float* wk = (const float*)d_in[49];
    const float* wv = (const float*)d_in[50];
    const float* f_w1 = (const float*)d_in[51];
    const float* f_b1 = (const float*)d_in[52];
    const float* f_w2 = (const float*)d_in[53];
    const float* f_b2 = (const float*)d_in[54];

    // workspace layout (~16.2 MB)
    float* ws   = (float*)d_ws;
    float* hr   = ws;                 // stage-2 graph0 hr
    float* hr2  = hr   + T_ * DH_;    // stage-2 graph1 hr
    float* qkva = hr2  + T_ * DH_;
    float* qkvb = qkva + T_ * 192;
    float* atta = qkvb + T_ * 192;
    float* attb = atta + T_ * DM_;    // also reused as stage-1 hr buffer
    float* x1f  = attb + T_ * DM_;
    float* x2f  = x1f  + T_ * DM_;
    float* x3f  = x2f  + T_ * DM_;
    unsigned short* Wfrag = (unsigned short*)(x3f + T_ * DM_);  // 3 graphs, 2.4 MB
    float* hr_r = attb;               // consumed before k_spatial4 writes attb

    // one-time permute of all three w2/b2 into bf16 B-fragment layout
    k_wconv<<<(3 * NG_ * NC_ * 64 + 255) / 256, 256, 0, stream>>>(
        mr_w2, mr_b2, ms0_w2, ms0_b2, ms1_w2, ms1_b2, Wfrag);

    // all three meta-hiddens depend only on c_x — one batched launch
    k_hr3<<<dim3(510, 3), 256, 0, stream>>>(c_x, mr_w1, mr_b1, ms0_w1, ms0_b1,
                                            ms1_w1, ms1_b1, hr_r, hr, hr2);

    // ---- stage 1: retnet retention ----
    k_meta_gemm2<<<dim3(64, 3, 1), 256, 0, stream>>>(
        hr_r, hr_r, x, Wfrag, Wfrag, qkva, qkva);
    k_retnet<<<B_ * N_, 256, 0, stream>>>(qkva, Dm, atta);
    k_gsl4<<<T_ / 8, 256, 0, stream>>>(atta, x, gr_W1, gr_W2, swr_wg, swr_bg,
                                       swr_wo, swr_bo, lnr_g, lnr_b, x1f);

    // ---- stage 2: spatial (predefined T + adaptive A) ----
    k_meta_gemm2<<<dim3(64, 3, 2), 256, 0, stream>>>(
        hr, hr2, x1f, Wfrag + WFRAG_G, Wfrag + 2 * WFRAG_G, qkva, qkvb);
    k_spatial4<<<dim3(B_ * P_, H_, 8), 256, 0, stream>>>(qkva, qkvb, Tm, Am, atta, attb);
    k_spatial_fuse4<<<T_ / 8, 256, 0, stream>>>(atta, attb, x1f,
                                                gs0_W1, gs0_W2, gs1_W1, gs1_W2,
                                                g2_W1, g2_W2, sws_wg, sws_bg,
                                                sws_wo, sws_bo, lns_g, lns_b, x2f);

    // ---- stage 3: temporal encoder-decoder attention ----
    k_qkvproj4<<<T_ / 8, 256, 0, stream>>>(x2f, enc, wq, wk, wv, qkva);
    k_temporal<<<B_ * N_, 256, 0, stream>>>(qkva, atta);
    k_gsl4<<<T_ / 8, 256, 0, stream>>>(atta, x2f, ge_W1, ge_W2, swe_wg, swe_bg,
                                       swe_wo, swe_bo, lne_g, lne_b, x3f);

    // ---- stage 4: FFN ----
    k_ffn4<<<T_ / 8, 256, 0, stream>>>(x3f, f_w1, f_b1, f_w2, f_b2, lnf_g, lnf_b,
                                       (float*)d_out);
}

// Round 11
// 344.975 us; speedup vs baseline: 1.1551x; 1.1551x over previous
//
#include <hip/hip_runtime.h>
#include <hip/hip_bf16.h>
#include <math.h>

namespace {

constexpr int B_ = 2, P_ = 12, N_ = 170, DM_ = 64, H_ = 8, DK_ = 8, DH_ = 32, DF_ = 256;
constexpr int T_ = B_ * P_ * N_;        // 4080 tokens = 255 x 16
constexpr float SQRT_DK = 2.8284271247461903f;

constexpr int NG_ = 12;                 // meta GEMM: 192 cols / 16
constexpr int NC_ = 66;                 // meta GEMM: 2112 K / 32
constexpr int WFRAG_G = NG_ * NC_ * 64 * 8;   // shorts per graph

// small-weight fragment arena: unit = 4096 shorts (one 64x64 matrix: 4ng x 2kc x 64 x 8)
// units: 0..5 swish {swr_wg,swr_wo,sws_wg,sws_wo,swe_wg,swe_wo}; 6..8 wq,wk,wv;
// 9..12 f_w1 (16ng x 2kc); 13..16 f_w2 (4ng x 8kc); 17..20 g2 {W1a,W1b,W2a,W2b};
// 21,29,37,45: gdc sets {gr,gs0,gs1,ge} (masked W1 4 units + W2 4 units each)
constexpr int WSM_UNITS = 53;

typedef __attribute__((ext_vector_type(4))) short short4v;
typedef __attribute__((ext_vector_type(8))) short short8v;
typedef __attribute__((ext_vector_type(4))) float float4v;

__device__ __forceinline__ unsigned short f2bf(float x) {
    union { float f; unsigned int u; } c; c.f = x;
    unsigned int r = (c.u + 0x7FFFu + ((c.u >> 16) & 1u)) >> 16;
    return (unsigned short)r;
}

// build bf16 A-fragment (token row = lane&15, k = quad*8+j) from fp32 row base
__device__ __forceinline__ short8v afrag(const float* rowbase, int kc, int quad) {
    const float* p = rowbase + kc * 32 + quad * 8;
    float4v a = *(const float4v*)p;
    float4v b = *(const float4v*)(p + 4);
    short8v f;
    f[0] = (short)f2bf(a.x); f[1] = (short)f2bf(a.y);
    f[2] = (short)f2bf(a.z); f[3] = (short)f2bf(a.w);
    f[4] = (short)f2bf(b.x); f[5] = (short)f2bf(b.y);
    f[6] = (short)f2bf(b.z); f[7] = (short)f2bf(b.w);
    return f;
}

// ---------- meta hidden (x3 batched) ----------
__global__ void k_hr3(const float* __restrict__ c_x,
                      const float* __restrict__ w1a, const float* __restrict__ b1a,
                      const float* __restrict__ w1b, const float* __restrict__ b1b,
                      const float* __restrict__ w1c, const float* __restrict__ b1c,
                      float* __restrict__ hra, float* __restrict__ hrb,
                      float* __restrict__ hrc) {
    int z = blockIdx.y;
    const float* w1 = z == 0 ? w1a : (z == 1 ? w1b : w1c);
    const float* b1 = z == 0 ? b1a : (z == 1 ? b1b : b1c);
    float* hr = z == 0 ? hra : (z == 1 ? hrb : hrc);
    int idx = blockIdx.x * 256 + threadIdx.x;
    if (idx >= T_ * DH_) return;
    int t = idx / DH_, j = idx % DH_;
    float acc = b1[j];
    const float* cx = c_x + t * DM_;
    #pragma unroll
    for (int d = 0; d < DM_; ++d) acc += cx[d] * w1[d * DH_ + j];
    hr[idx] = fmaxf(acc, 0.f);
}

// ---------- one-time meta w2/b2 -> bf16 B-fragment-linear ----------
__global__ void k_wconv(const float* __restrict__ w2a, const float* __restrict__ b2a,
                        const float* __restrict__ w2b, const float* __restrict__ b2b,
                        const float* __restrict__ w2c, const float* __restrict__ b2c,
                        unsigned short* __restrict__ Wfrag) {
    int idx = blockIdx.x * 256 + threadIdx.x;
    if (idx >= 3 * NG_ * NC_ * 64) return;
    int lane = idx & 63;
    int c = (idx >> 6) % NC_;
    int ng = (idx >> 6) / NC_ % NG_;
    int g = idx / (64 * NC_ * NG_);
    const float* w2 = g == 0 ? w2a : (g == 1 ? w2b : w2c);
    const float* b2 = g == 0 ? b2a : (g == 1 ? b2b : b2c);
    int m = ng * 16 + (lane & 15);
    int u = c >> 1;
    int d0 = (c & 1) * 32 + (lane >> 4) * 8;
    const float* src = (u < DH_) ? (w2 + u * 12288 + m * 64 + d0) : (b2 + m * 64 + d0);
    short8v o;
    #pragma unroll
    for (int j = 0; j < 8; ++j) o[j] = (short)f2bf(src[j]);
    *(short8v*)(Wfrag + (size_t)idx * 8) = o;
}

// ---------- one-time small-weight -> bf16 B-fragment permute (19 jobs) ----------
__global__ void k_wconv2(
    const float* swr_wg, const float* swr_wo, const float* sws_wg, const float* sws_wo,
    const float* swe_wg, const float* swe_wo,
    const float* wq, const float* wk, const float* wv,
    const float* f_w1, const float* f_w2,
    const float* g2_W1, const float* g2_W2,
    const float* gr_W1, const float* gr_W2, const float* gs0_W1, const float* gs0_W2,
    const float* gs1_W1, const float* gs1_W2, const float* ge_W1, const float* ge_W2,
    unsigned short* __restrict__ Wsm) {
    const int job = blockIdx.y;
    const int idx = blockIdx.x * 256 + threadIdx.x;
    const float* s1 = nullptr; const float* s2 = nullptr;
    int dst = 0, KC = 2, NG = 4, N = 64, kind = 0;
    switch (job) {
        case 0:  s1 = swr_wg; dst = 0; break;
        case 1:  s1 = swr_wo; dst = 1; break;
        case 2:  s1 = sws_wg; dst = 2; break;
        case 3:  s1 = sws_wo; dst = 3; break;
        case 4:  s1 = swe_wg; dst = 4; break;
        case 5:  s1 = swe_wo; dst = 5; break;
        case 6:  s1 = wq; dst = 6; break;
        case 7:  s1 = wk; dst = 7; break;
        case 8:  s1 = wv; dst = 8; break;
        case 9:  s1 = f_w1; dst = 9;  NG = 16; N = 256; break;
        case 10: s1 = f_w2; dst = 13; KC = 8; break;
        case 11: s1 = g2_W1;        dst = 17; break;
        case 12: s1 = g2_W1 + 4096; dst = 18; break;
        case 13: s1 = g2_W2;        dst = 19; break;
        case 14: s1 = g2_W2 + 4096; dst = 20; break;
        case 15: s1 = gr_W1;  s2 = gr_W2;  dst = 21; kind = 1; break;
        case 16: s1 = gs0_W1; s2 = gs0_W2; dst = 29; kind = 1; break;
        case 17: s1 = gs1_W1; s2 = gs1_W2; dst = 37; kind = 1; break;
        default: s1 = ge_W1;  s2 = ge_W2;  dst = 45; kind = 1; break;
    }
    if (kind == 0) {
        if (idx >= NG * KC * 64) return;
        int lane = idx & 63;
        int kc = (idx >> 6) % KC, ng = (idx >> 6) / KC;
        int krow = kc * 32 + (lane >> 4) * 8;
        int n = ng * 16 + (lane & 15);
        short8v o;
        #pragma unroll
        for (int j = 0; j < 8; ++j) o[j] = (short)f2bf(s1[(krow + j) * N + n]);
        *(short8v*)(Wsm + (size_t)dst * 4096 + (size_t)idx * 8) = o;
    } else {
        if (idx >= 8 * 4 * 64) return;
        int lane = idx & 63;
        int ng = (idx >> 6) & 3, g = idx >> 8;
        int quad = lane >> 4, n = ng * 16 + (lane & 15);
        short8v o1 = {0,0,0,0,0,0,0,0}, o2 = {0,0,0,0,0,0,0,0};
        if (quad == (g & 3)) {
            #pragma unroll
            for (int j = 0; j < 8; ++j) {
                o1[j] = (short)f2bf(s1[(g * 8 + j) * 64 + n]);
                o2[j] = (short)f2bf(s2[(g * 8 + j) * 64 + n]);
            }
        }
        size_t off = (size_t)dst * 4096 + (size_t)idx * 8;
        *(short8v*)(Wsm + off) = o1;
        *(short8v*)(Wsm + off + 16384) = o2;
    }
}

// ---------- meta+mhlin GEMM (proven): no LDS, no barriers ----------
__global__ __launch_bounds__(256) void k_meta_gemm2(
    const float* __restrict__ hr0, const float* __restrict__ hr1,
    const float* __restrict__ xin,
    const unsigned short* __restrict__ Wf0, const unsigned short* __restrict__ Wf1,
    float* __restrict__ out0, float* __restrict__ out1) {
    const int bz = blockIdx.z;
    const float* hr = bz ? hr1 : hr0;
    const unsigned short* Wf = bz ? Wf1 : Wf0;
    float* out = bz ? out1 : out0;

    const int tid = threadIdx.x;
    const int wv = tid >> 6, lane = tid & 63;
    const int l15 = lane & 15, quad = lane >> 4;
    const int g16 = blockIdx.x * 4 + wv;
    if (g16 >= 255) return;
    const int t = g16 * 16 + l15;
    const int nb = blockIdx.y;

    const float* xp = xin + t * 64 + quad * 8;
    float4v xa = *(const float4v*)(xp);
    float4v xb = *(const float4v*)(xp + 4);
    float4v xc = *(const float4v*)(xp + 32);
    float4v xd = *(const float4v*)(xp + 36);
    float xr[16] = {xa.x, xa.y, xa.z, xa.w, xb.x, xb.y, xb.z, xb.w,
                    xc.x, xc.y, xc.z, xc.w, xd.x, xd.y, xd.z, xd.w};

    const float* hrp = hr + t * 32;
    float4v acc[4] = {{0.f,0.f,0.f,0.f},{0.f,0.f,0.f,0.f},
                      {0.f,0.f,0.f,0.f},{0.f,0.f,0.f,0.f}};

    const unsigned short* wb = Wf + ((size_t)(nb * 4) * NC_ * 64 + lane) * 8;
    const size_t qstride = (size_t)NC_ * 64 * 8;
    const size_t cstride = 64 * 8;

    for (int u = 0; u < 33; ++u) {
        float hrv = (u < DH_) ? hrp[u] : 1.0f;
        short8v a0, a1;
        #pragma unroll
        for (int j = 0; j < 8; ++j) {
            a0[j] = (short)f2bf(hrv * xr[j]);
            a1[j] = (short)f2bf(hrv * xr[8 + j]);
        }
        const unsigned short* wc = wb + (size_t)(2 * u) * cstride;
        #pragma unroll
        for (int q = 0; q < 4; ++q) {
            short8v b0 = *(const short8v*)(wc + q * qstride);
            short8v b1 = *(const short8v*)(wc + q * qstride + cstride);
            acc[q] = __builtin_amdgcn_mfma_f32_16x16x32_bf16(a0, b0, acc[q], 0, 0, 0);
            acc[q] = __builtin_amdgcn_mfma_f32_16x16x32_bf16(a1, b1, acc[q], 0, 0, 0);
        }
    }

    #pragma unroll
    for (int q = 0; q < 4; ++q) {
        #pragma unroll
        for (int r = 0; r < 4; ++r) {
            int tt = g16 * 16 + quad * 4 + r;
            out[tt * 192 + nb * 64 + q * 16 + l15] = acc[q][r];
        }
    }
}

// ---------- retnet temporal retention (unchanged) ----------
__global__ __launch_bounds__(256) void k_retnet(const float* __restrict__ qkv,
                                                const float* __restrict__ Dm,
                                                float* __restrict__ att) {
    const int bn = blockIdx.x;
    const int b = bn / N_, n = bn % N_;
    __shared__ float S[12][192];
    __shared__ float Ds[8 * 145];
    const int tid = threadIdx.x;
    for (int e = tid; e < 12 * 192; e += 256) {
        int p = e / 192, c = e % 192;
        S[p][c] = qkv[((size_t)((b * P_ + p) * N_ + n)) * 192 + c];
    }
    for (int e = tid; e < 1152; e += 256) {
        Ds[(e / 144) * 145 + (e % 144)] = Dm[e];
    }
    __syncthreads();
    const int qq = tid >> 6;
    const int lane = tid & 63;
    const int h = lane >> 3, k = lane & 7;
    for (int q = qq; q < P_; q += 4) {
        float Qv = S[q][h * 8 + k];
        float r[P_];
        float rsum = 0.f;
        #pragma unroll
        for (int p = 0; p < P_; ++p) {
            float prod = Qv * S[p][64 + h * 8 + k];
            prod += __shfl_xor(prod, 1, 64);
            prod += __shfl_xor(prod, 2, 64);
            prod += __shfl_xor(prod, 4, 64);
            float s = (prod / SQRT_DK) * Ds[h * 145 + q * 12 + p];
            r[p] = s; rsum += s;
        }
        float rs = fmaxf(fabsf(rsum), 1.0f);
        float acc = 0.f;
        #pragma unroll
        for (int p = 0; p < P_; ++p) acc += (r[p] / rs) * S[p][128 + h * 8 + k];
        att[((size_t)((b * P_ + q) * N_ + n)) * 64 + lane] = acc;
    }
}

// ---------- temporal enc-dec attention (unchanged) ----------
__global__ __launch_bounds__(256) void k_temporal(const float* __restrict__ qkv,
                                                  float* __restrict__ att) {
    const int bn = blockIdx.x;
    const int b = bn / N_, n = bn % N_;
    __shared__ float S[12][192];
    const int tid = threadIdx.x;
    for (int e = tid; e < 12 * 192; e += 256) {
        int p = e / 192, c = e % 192;
        S[p][c] = qkv[((size_t)((b * P_ + p) * N_ + n)) * 192 + c];
    }
    __syncthreads();
    const int qq = tid >> 6;
    const int lane = tid & 63;
    const int h = lane >> 3, k = lane & 7;
    for (int q = qq; q < P_; q += 4) {
        float Qv = S[q][h * 8 + k];
        float s[P_];
        float mx = -1e30f;
        #pragma unroll
        for (int p = 0; p < P_; ++p) {
            float prod = Qv * S[p][64 + h * 8 + k];
            prod += __shfl_xor(prod, 1, 64);
            prod += __shfl_xor(prod, 2, 64);
            prod += __shfl_xor(prod, 4, 64);
            float v = prod / SQRT_DK;
            s[p] = v; mx = fmaxf(mx, v);
        }
        float den = 0.f, acc = 0.f;
        #pragma unroll
        for (int p = 0; p < P_; ++p) {
            float e = expf(s[p] - mx);
            den += e;
            acc += e * S[p][128 + h * 8 + k];
        }
        att[((size_t)((b * P_ + q) * N_ + n)) * 64 + lane] = acc / den;
    }
}

// ---------- spatial attention v4 (unchanged) ----------
__global__ __launch_bounds__(256) void k_spatial4(
    const float* __restrict__ qkvA, const float* __restrict__ qkvB,
    const float* __restrict__ Tm, const float* __restrict__ Am,
    float* __restrict__ attA, float* __restrict__ attB) {
    const int bp = blockIdx.x;
    const int h = blockIdx.y;
    const int g = blockIdx.z >> 2;
    const int ic = blockIdx.z & 3;
    const float* qkv = g ? qkvB : qkvA;
    float* att = g ? attB : attA;

    __shared__ float sKt[8][192];
    __shared__ float sV[192][8];
    __shared__ float sW[4][192];

    const int tid = threadIdx.x;
    for (int e = tid; e < 384; e += 256) {
        int j = e >> 1, kh = (e & 1) * 4;
        float4v k4 = {0.f, 0.f, 0.f, 0.f}, v4 = k4;
        if (j < N_) {
            const float* row = qkv + (size_t)(bp * N_ + j) * 192 + h * 8 + kh;
            k4 = *(const float4v*)(row + 64);
            v4 = *(const float4v*)(row + 128);
        }
        sKt[kh + 0][j] = k4.x;
        sKt[kh + 1][j] = k4.y;
        sKt[kh + 2][j] = k4.z;
        sKt[kh + 3][j] = k4.w;
        *(float4v*)&sV[j][kh] = v4;
    }
    __syncthreads();

    const int wv = tid >> 6;
    const int lane = tid & 63;
    const int j8 = lane >> 3, kk = lane & 7;

    const int i0 = ic * 43;
    const int i1 = (i0 + 43 < N_) ? (i0 + 43) : N_;

    for (int i = i0 + wv; i < i1; i += 4) {
        const float* qrow = qkv + (size_t)(bp * N_ + i) * 192 + h * 8;
        float4v qa = *(const float4v*)qrow;
        float4v qb = *(const float4v*)(qrow + 4);
        float Qi[8] = {qa.x, qa.y, qa.z, qa.w, qb.x, qb.y, qb.z, qb.w};
        const float* Trow = g ? (Am + (size_t)(bp * N_ + i) * N_) : (Tm + (size_t)i * N_);

        float sloc[3], tloc[3];
        float mx = -1e30f;
        #pragma unroll
        for (int c = 0; c < 3; ++c) {
            int j = c * 64 + lane;
            float tv = 0.f, s = -1e30f;
            if (j < N_) {
                tv = Trow[j];
                if (tv != 0.f) {
                    float dot = 0.f;
                    #pragma unroll
                    for (int k = 0; k < 8; ++k) dot += Qi[k] * sKt[k][j];
                    s = dot / SQRT_DK;
                } else {
                    s = 0.f;
                }
            }
            sloc[c] = s; tloc[c] = tv;
            mx = fmaxf(mx, s);
        }
        #pragma unroll
        for (int off = 1; off < 64; off <<= 1) mx = fmaxf(mx, __shfl_xor(mx, off, 64));

        float den = 0.f;
        #pragma unroll
        for (int c = 0; c < 3; ++c) {
            float s = sloc[c];
            float e = (s != 0.f) ? expf(s - mx) : 0.f;
            den += e;
            sW[wv][c * 64 + lane] = e * tloc[c];
        }
        #pragma unroll
        for (int off = 1; off < 64; off <<= 1) den += __shfl_xor(den, off, 64);

        float acc = 0.f;
        #pragma unroll 4
        for (int j = j8; j < 192; j += 8) acc += sW[wv][j] * sV[j][kk];
        acc += __shfl_xor(acc, 8, 64);
        acc += __shfl_xor(acc, 16, 64);
        acc += __shfl_xor(acc, 32, 64);
        if (lane < 8)
            att[(size_t)(bp * N_ + i) * 64 + h * 8 + lane] = acc / (den + 1e-5f);
    }
}

// gdc via masked MFMA frags + online (exp-direct) combine; outputs num/den (C-layout)
__device__ __forceinline__ void gdc_mfma(const short8v* attf,
                                         const unsigned short* gdcW, int lane,
                                         float4v* num, float4v* den) {
    #pragma unroll
    for (int q = 0; q < 4; ++q) {
        num[q] = (float4v){0.f, 0.f, 0.f, 0.f};
        den[q] = (float4v){0.f, 0.f, 0.f, 0.f};
    }
    for (int g = 0; g < 8; ++g) {
        const unsigned short* wb = gdcW + ((size_t)(g * 4) * 64 + lane) * 8;
        short8v af = attf[g >> 2];
        float4v a[4], s[4];
        #pragma unroll
        for (int q = 0; q < 4; ++q) {
            a[q] = (float4v){0.f, 0.f, 0.f, 0.f};
            s[q] = (float4v){0.f, 0.f, 0.f, 0.f};
        }
        #pragma unroll
        for (int q = 0; q < 4; ++q) {
            short8v b1 = *(const short8v*)(wb + q * 512);
            short8v b2 = *(const short8v*)(wb + 16384 + q * 512);
            a[q] = __builtin_amdgcn_mfma_f32_16x16x32_bf16(af, b1, a[q], 0, 0, 0);
            s[q] = __builtin_amdgcn_mfma_f32_16x16x32_bf16(af, b2, s[q], 0, 0, 0);
        }
        #pragma unroll
        for (int q = 0; q < 4; ++q) {
            #pragma unroll
            for (int r = 0; r < 4; ++r) {
                float e = __expf(fmaxf(s[q][r], 0.f));
                den[q][r] += e;
                num[q][r] += a[q][r] * e;
            }
        }
    }
}

// ---------- gsl v5: MFMA tail (gdc + gate + wo + LN), wave = 16 tokens ----------
__global__ __launch_bounds__(256) void k_gsl5(
    const float* __restrict__ att, const float* __restrict__ xin,
    const unsigned short* __restrict__ gdcW,
    const unsigned short* __restrict__ gateW, const unsigned short* __restrict__ woW,
    const float* __restrict__ bg, const float* __restrict__ bo,
    const float* __restrict__ lng, const float* __restrict__ lnb,
    float* __restrict__ xout) {
    __shared__ unsigned short swl[4][16][72];
    const int tid = threadIdx.x, wv = tid >> 6, lane = tid & 63;
    const int l15 = lane & 15, quad = lane >> 4;
    const int g16 = blockIdx.x * 4 + wv;
    if (g16 >= 255) return;
    const int t = g16 * 16 + l15;

    short8v attf[2], xf[2];
    #pragma unroll
    for (int kc = 0; kc < 2; ++kc) {
        attf[kc] = afrag(att + (size_t)t * 64, kc, quad);
        xf[kc]   = afrag(xin + (size_t)t * 64, kc, quad);
    }

    float4v num[4], den[4];
    gdc_mfma(attf, gdcW, lane, num, den);

    float4v hg[4];
    #pragma unroll
    for (int q = 0; q < 4; ++q) hg[q] = (float4v){0.f, 0.f, 0.f, 0.f};
    #pragma unroll
    for (int kc = 0; kc < 2; ++kc)
        #pragma unroll
        for (int q = 0; q < 4; ++q)
            hg[q] = __builtin_amdgcn_mfma_f32_16x16x32_bf16(
                xf[kc], *(const short8v*)(gateW + ((size_t)(q * 2 + kc) * 64 + lane) * 8),
                hg[q], 0, 0, 0);

    float bgq[4];
    #pragma unroll
    for (int q = 0; q < 4; ++q) bgq[q] = bg[q * 16 + l15];
    #pragma unroll
    for (int q = 0; q < 4; ++q)
        #pragma unroll
        for (int r = 0; r < 4; ++r) {
            float v = (hg[q][r] + bgq[q]) * (num[q][r] / den[q][r]);
            float sw = v / (1.f + __expf(-v));
            swl[wv][quad * 4 + r][q * 16 + l15] = f2bf(sw);
        }
    short8v swf0 = *(const short8v*)&swl[wv][l15][quad * 8];
    short8v swf1 = *(const short8v*)&swl[wv][l15][32 + quad * 8];

    float4v ov[4];
    #pragma unroll
    for (int q = 0; q < 4; ++q) ov[q] = (float4v){0.f, 0.f, 0.f, 0.f};
    #pragma unroll
    for (int q = 0; q < 4; ++q) {
        ov[q] = __builtin_amdgcn_mfma_f32_16x16x32_bf16(
            swf0, *(const short8v*)(woW + ((size_t)(q * 2 + 0) * 64 + lane) * 8), ov[q], 0, 0, 0);
        ov[q] = __builtin_amdgcn_mfma_f32_16x16x32_bf16(
            swf1, *(const short8v*)(woW + ((size_t)(q * 2 + 1) * 64 + lane) * 8), ov[q], 0, 0, 0);
    }

    float boq[4], lgq[4], lbq[4];
    #pragma unroll
    for (int q = 0; q < 4; ++q) {
        boq[q] = bo[q * 16 + l15]; lgq[q] = lng[q * 16 + l15]; lbq[q] = lnb[q * 16 + l15];
    }
    float v[4][4];
    #pragma unroll
    for (int q = 0; q < 4; ++q)
        #pragma unroll
        for (int r = 0; r < 4; ++r)
            v[q][r] = ov[q][r] + boq[q]
                    + xin[(size_t)(g16 * 16 + quad * 4 + r) * 64 + q * 16 + l15];
    #pragma unroll
    for (int r = 0; r < 4; ++r) {
        float s1 = 0.f, s2 = 0.f;
        #pragma unroll
        for (int q = 0; q < 4; ++q) { s1 += v[q][r]; s2 += v[q][r] * v[q][r]; }
        #pragma unroll
        for (int off = 1; off < 16; off <<= 1) {
            s1 += __shfl_xor(s1, off, 64);
            s2 += __shfl_xor(s2, off, 64);
        }
        float m = s1 * (1.f / 64.f);
        float var = s2 * (1.f / 64.f) - m * m;
        float inv = rsqrtf(var + 1e-5f);
        int tt = g16 * 16 + quad * 4 + r;
        #pragma unroll
        for (int q = 0; q < 4; ++q)
            xout[(size_t)tt * 64 + q * 16 + l15] = (v[q][r] - m) * inv * lgq[q] + lbq[q];
    }
}

// ---------- spatial tail v5: 2x gdc + g2 + gate + wo + LN ----------
__global__ __launch_bounds__(256) void k_spatial_fuse5(
    const float* __restrict__ att0, const float* __restrict__ att1,
    const float* __restrict__ x1,
    const unsigned short* __restrict__ gdc0W, const unsigned short* __restrict__ gdc1W,
    const unsigned short* __restrict__ g2W1a, const unsigned short* __restrict__ g2W1b,
    const unsigned short* __restrict__ g2W2a, const unsigned short* __restrict__ g2W2b,
    const unsigned short* __restrict__ gateW, const unsigned short* __restrict__ woW,
    const float* __restrict__ bg, const float* __restrict__ bo,
    const float* __restrict__ lng, const float* __restrict__ lnb,
    float* __restrict__ xout) {
    __shared__ unsigned short o0l[4][16][72], o1l[4][16][72], swl[4][16][72];
    const int tid = threadIdx.x, wv = tid >> 6, lane = tid & 63;
    const int l15 = lane & 15, quad = lane >> 4;
    const int g16 = blockIdx.x * 4 + wv;
    if (g16 >= 255) return;
    const int t = g16 * 16 + l15;

    short8v a0f[2], a1f[2], xf[2];
    #pragma unroll
    for (int kc = 0; kc < 2; ++kc) {
        a0f[kc] = afrag(att0 + (size_t)t * 64, kc, quad);
        a1f[kc] = afrag(att1 + (size_t)t * 64, kc, quad);
        xf[kc]  = afrag(x1   + (size_t)t * 64, kc, quad);
    }
    {
        float4v n0[4], d0[4];
        gdc_mfma(a0f, gdc0W, lane, n0, d0);
        #pragma unroll
        for (int q = 0; q < 4; ++q)
            #pragma unroll
            for (int r = 0; r < 4; ++r)
                o0l[wv][quad * 4 + r][q * 16 + l15] = f2bf(n0[q][r] / d0[q][r]);
    }
    {
        float4v n1[4], d1[4];
        gdc_mfma(a1f, gdc1W, lane, n1, d1);
        #pragma unroll
        for (int q = 0; q < 4; ++q)
            #pragma unroll
            for (int r = 0; r < 4; ++r)
                o1l[wv][quad * 4 + r][q * 16 + l15] = f2bf(n1[q][r] / d1[q][r]);
    }
    short8v o0f[2], o1f[2];
    o0f[0] = *(const short8v*)&o0l[wv][l15][quad * 8];
    o0f[1] = *(const short8v*)&o0l[wv][l15][32 + quad * 8];
    o1f[0] = *(const short8v*)&o1l[wv][l15][quad * 8];
    o1f[1] = *(const short8v*)&o1l[wv][l15][32 + quad * 8];

    float4v A0[4], S0[4], A1[4], S1[4];
    #pragma unroll
    for (int q = 0; q < 4; ++q) {
        A0[q] = (float4v){0.f,0.f,0.f,0.f}; S0[q] = A0[q]; A1[q] = A0[q]; S1[q] = A0[q];
    }
    #pragma unroll
    for (int kc = 0; kc < 2; ++kc)
        #pragma unroll
        for (int q = 0; q < 4; ++q) {
            size_t fo = ((size_t)(q * 2 + kc) * 64 + lane) * 8;
            A0[q] = __builtin_amdgcn_mfma_f32_16x16x32_bf16(o0f[kc], *(const short8v*)(g2W1a + fo), A0[q], 0, 0, 0);
            S0[q] = __builtin_amdgcn_mfma_f32_16x16x32_bf16(o0f[kc], *(const short8v*)(g2W2a + fo), S0[q], 0, 0, 0);
            A1[q] = __builtin_amdgcn_mfma_f32_16x16x32_bf16(o1f[kc], *(const short8v*)(g2W1b + fo), A1[q], 0, 0, 0);
            S1[q] = __builtin_amdgcn_mfma_f32_16x16x32_bf16(o1f[kc], *(const short8v*)(g2W2b + fo), S1[q], 0, 0, 0);
        }
    float og[4][4];
    #pragma unroll
    for (int q = 0; q < 4; ++q)
        #pragma unroll
        for (int r = 0; r < 4; ++r) {
            float e0 = __expf(fmaxf(S0[q][r], 0.f));
            float e1 = __expf(fmaxf(S1[q][r], 0.f));
            og[q][r] = (A0[q][r] * e0 + A1[q][r] * e1) / (e0 + e1);
        }

    float4v hg[4];
    #pragma unroll
    for (int q = 0; q < 4; ++q) hg[q] = (float4v){0.f,0.f,0.f,0.f};
    #pragma unroll
    for (int kc = 0; kc < 2; ++kc)
        #pragma unroll
        for (int q = 0; q < 4; ++q)
            hg[q] = __builtin_amdgcn_mfma_f32_16x16x32_bf16(
                xf[kc], *(const short8v*)(gateW + ((size_t)(q * 2 + kc) * 64 + lane) * 8),
                hg[q], 0, 0, 0);
    float bgq[4];
    #pragma unroll
    for (int q = 0; q < 4; ++q) bgq[q] = bg[q * 16 + l15];
    #pragma unroll
    for (int q = 0; q < 4; ++q)
        #pragma unroll
        for (int r = 0; r < 4; ++r) {
            float vv = (hg[q][r] + bgq[q]) * og[q][r];
            float sw = vv / (1.f + __expf(-vv));
            swl[wv][quad * 4 + r][q * 16 + l15] = f2bf(sw);
        }
    short8v swf0 = *(const short8v*)&swl[wv][l15][quad * 8];
    short8v swf1 = *(const short8v*)&swl[wv][l15][32 + quad * 8];

    float4v ov[4];
    #pragma unroll
    for (int q = 0; q < 4; ++q) ov[q] = (float4v){0.f,0.f,0.f,0.f};
    #pragma unroll
    for (int q = 0; q < 4; ++q) {
        ov[q] = __builtin_amdgcn_mfma_f32_16x16x32_bf16(
            swf0, *(const short8v*)(woW + ((size_t)(q * 2 + 0) * 64 + lane) * 8), ov[q], 0, 0, 0);
        ov[q] = __builtin_amdgcn_mfma_f32_16x16x32_bf16(
            swf1, *(const short8v*)(woW + ((size_t)(q * 2 + 1) * 64 + lane) * 8), ov[q], 0, 0, 0);
    }
    float boq[4], lgq[4], lbq[4];
    #pragma unroll
    for (int q = 0; q < 4; ++q) {
        boq[q] = bo[q * 16 + l15]; lgq[q] = lng[q * 16 + l15]; lbq[q] = lnb[q * 16 + l15];
    }
    float v[4][4];
    #pragma unroll
    for (int q = 0; q < 4; ++q)
        #pragma unroll
        for (int r = 0; r < 4; ++r)
            v[q][r] = ov[q][r] + boq[q]
                    + x1[(size_t)(g16 * 16 + quad * 4 + r) * 64 + q * 16 + l15];
    #pragma unroll
    for (int r = 0; r < 4; ++r) {
        float s1 = 0.f, s2 = 0.f;
        #pragma unroll
        for (int q = 0; q < 4; ++q) { s1 += v[q][r]; s2 += v[q][r] * v[q][r]; }
        #pragma unroll
        for (int off = 1; off < 16; off <<= 1) {
            s1 += __shfl_xor(s1, off, 64);
            s2 += __shfl_xor(s2, off, 64);
        }
        float m = s1 * (1.f / 64.f);
        float var = s2 * (1.f / 64.f) - m * m;
        float inv = rsqrtf(var + 1e-5f);
        int tt = g16 * 16 + quad * 4 + r;
        #pragma unroll
        for (int q = 0; q < 4; ++q)
            xout[(size_t)tt * 64 + q * 16 + l15] = (v[q][r] - m) * inv * lgq[q] + lbq[q];
    }
}

// ---------- qkv projection v5: 3 GEMMs via MFMA ----------
__global__ __launch_bounds__(256) void k_qkvproj5(
    const float* __restrict__ x2, const float* __restrict__ enc,
    const unsigned short* __restrict__ wqF, const unsigned short* __restrict__ wkF,
    const unsigned short* __restrict__ wvF,
    float* __restrict__ qkv) {
    const int tid = threadIdx.x, wv = tid >> 6, lane = tid & 63;
    const int l15 = lane & 15, quad = lane >> 4;
    const int g16 = blockIdx.x * 4 + wv;
    if (g16 >= 255) return;
    const int t = g16 * 16 + l15;
    short8v xf[2], ef[2];
    #pragma unroll
    for (int kc = 0; kc < 2; ++kc) {
        xf[kc] = afrag(x2 + (size_t)t * 64, kc, quad);
        ef[kc] = afrag(enc + (size_t)t * 64, kc, quad);
    }
    #pragma unroll
    for (int seg = 0; seg < 3; ++seg) {
        const unsigned short* W = seg == 0 ? wqF : (seg == 1 ? wkF : wvF);
        const short8v* af = seg == 0 ? xf : ef;
        float4v ac[4];
        #pragma unroll
        for (int q = 0; q < 4; ++q) ac[q] = (float4v){0.f,0.f,0.f,0.f};
        #pragma unroll
        for (int kc = 0; kc < 2; ++kc)
            #pragma unroll
            for (int q = 0; q < 4; ++q)
                ac[q] = __builtin_amdgcn_mfma_f32_16x16x32_bf16(
                    af[kc], *(const short8v*)(W + ((size_t)(q * 2 + kc) * 64 + lane) * 8),
                    ac[q], 0, 0, 0);
        #pragma unroll
        for (int q = 0; q < 4; ++q)
            #pragma unroll
            for (int r = 0; r < 4; ++r)
                qkv[(size_t)(g16 * 16 + quad * 4 + r) * 192 + seg * 64 + q * 16 + l15]
                    = ac[q][r];
    }
}

// ---------- FFN v5: w1(64x256) + relu + w2(256x64) + LN via MFMA ----------
__global__ __launch_bounds__(256) void k_ffn5(
    const float* __restrict__ x3,
    const unsigned short* __restrict__ w1F, const float* __restrict__ b1,
    const unsigned short* __restrict__ w2F, const float* __restrict__ b2,
    const float* __restrict__ lng, const float* __restrict__ lnb,
    float* __restrict__ out) {
    __shared__ unsigned short hl[4][16][264];
    const int tid = threadIdx.x, wv = tid >> 6, lane = tid & 63;
    const int l15 = lane & 15, quad = lane >> 4;
    const int g16 = blockIdx.x * 4 + wv;
    if (g16 >= 255) return;
    const int t = g16 * 16 + l15;
    short8v xf[2];
    xf[0] = afrag(x3 + (size_t)t * 64, 0, quad);
    xf[1] = afrag(x3 + (size_t)t * 64, 1, quad);

    float4v h[16];
    #pragma unroll
    for (int ng = 0; ng < 16; ++ng) h[ng] = (float4v){0.f,0.f,0.f,0.f};
    #pragma unroll
    for (int kc = 0; kc < 2; ++kc)
        #pragma unroll
        for (int ng = 0; ng < 16; ++ng)
            h[ng] = __builtin_amdgcn_mfma_f32_16x16x32_bf16(
                xf[kc], *(const short8v*)(w1F + ((size_t)(ng * 2 + kc) * 64 + lane) * 8),
                h[ng], 0, 0, 0);
    #pragma unroll
    for (int ng = 0; ng < 16; ++ng) {
        float b1v = b1[ng * 16 + l15];
        #pragma unroll
        for (int r = 0; r < 4; ++r)
            hl[wv][quad * 4 + r][ng * 16 + l15] = f2bf(fmaxf(h[ng][r] + b1v, 0.f));
    }
    float4v ov[4];
    #pragma unroll
    for (int q = 0; q < 4; ++q) ov[q] = (float4v){0.f,0.f,0.f,0.f};
    #pragma unroll
    for (int kc = 0; kc < 8; ++kc) {
        short8v hf = *(const short8v*)&hl[wv][l15][kc * 32 + quad * 8];
        #pragma unroll
        for (int q = 0; q < 4; ++q)
            ov[q] = __builtin_amdgcn_mfma_f32_16x16x32_bf16(
                hf, *(const short8v*)(w2F + ((size_t)(q * 8 + kc) * 64 + lane) * 8),
                ov[q], 0, 0, 0);
    }
    float boq[4], lgq[4], lbq[4];
    #pragma unroll
    for (int q = 0; q < 4; ++q) {
        boq[q] = b2[q * 16 + l15]; lgq[q] = lng[q * 16 + l15]; lbq[q] = lnb[q * 16 + l15];
    }
    float v[4][4];
    #pragma unroll
    for (int q = 0; q < 4; ++q)
        #pragma unroll
        for (int r = 0; r < 4; ++r)
            v[q][r] = ov[q][r] + boq[q]
                    + x3[(size_t)(g16 * 16 + quad * 4 + r) * 64 + q * 16 + l15];
    #pragma unroll
    for (int r = 0; r < 4; ++r) {
        float s1 = 0.f, s2 = 0.f;
        #pragma unroll
        for (int q = 0; q < 4; ++q) { s1 += v[q][r]; s2 += v[q][r] * v[q][r]; }
        #pragma unroll
        for (int off = 1; off < 16; off <<= 1) {
            s1 += __shfl_xor(s1, off, 64);
            s2 += __shfl_xor(s2, off, 64);
        }
        float m = s1 * (1.f / 64.f);
        float var = s2 * (1.f / 64.f) - m * m;
        float inv = rsqrtf(var + 1e-5f);
        int tt = g16 * 16 + quad * 4 + r;
        #pragma unroll
        for (int q = 0; q < 4; ++q)
            out[(size_t)tt * 64 + q * 16 + l15] = (v[q][r] - m) * inv * lgq[q] + lbq[q];
    }
}

} // namespace

extern "C" void kernel_launch(void* const* d_in, const int* in_sizes, int n_in,
                              void* d_out, int out_size, void* d_ws, size_t ws_size,
                              hipStream_t stream) {
    (void)in_sizes; (void)n_in; (void)out_size; (void)ws_size;
    const float* x    = (const float*)d_in[0];
    const float* c_x  = (const float*)d_in[1];
    const float* enc  = (const float*)d_in[2];
    const float* Tm   = (const float*)d_in[3];
    const float* Am   = (const float*)d_in[4];
    const float* Dm   = (const float*)d_in[5];
    const float* mr_w1 = (const float*)d_in[6];
    const float* mr_b1 = (const float*)d_in[7];
    const float* mr_w2 = (const float*)d_in[8];
    const float* mr_b2 = (const float*)d_in[9];
    const float* ms0_w1 = (const float*)d_in[10];
    const float* ms0_b1 = (const float*)d_in[11];
    const float* ms0_w2 = (const float*)d_in[12];
    const float* ms0_b2 = (const float*)d_in[13];
    const float* ms1_w1 = (const float*)d_in[14];
    const float* ms1_b1 = (const float*)d_in[15];
    const float* ms1_w2 = (const float*)d_in[16];
    const float* ms1_b2 = (const float*)d_in[17];
    const float* gr_W1 = (const float*)d_in[18];
    const float* gr_W2 = (const float*)d_in[19];
    const float* gs0_W1 = (const float*)d_in[20];
    const float* gs0_W2 = (const float*)d_in[21];
    const float* gs1_W1 = (const float*)d_in[22];
    const float* gs1_W2 = (const float*)d_in[23];
    const float* g2_W1 = (const float*)d_in[24];
    const float* g2_W2 = (const float*)d_in[25];
    const float* ge_W1 = (const float*)d_in[26];
    const float* ge_W2 = (const float*)d_in[27];
    const float* swr_wg = (const float*)d_in[28];
    const float* swr_bg = (const float*)d_in[29];
    const float* swr_wo = (const float*)d_in[30];
    const float* swr_bo = (const float*)d_in[31];
    const float* sws_wg = (const float*)d_in[32];
    const float* sws_bg = (const float*)d_in[33];
    const float* sws_wo = (const float*)d_in[34];
    const float* sws_bo = (const float*)d_in[35];
    const float* swe_wg = (const float*)d_in[36];
    const float* swe_bg = (const float*)d_in[37];
    const float* swe_wo = (const float*)d_in[38];
    const float* swe_bo = (const float*)d_in[39];
    const float* lnr_g = (const float*)d_in[40];
    const float* lnr_b = (const float*)d_in[41];
    const float* lns_g = (const float*)d_in[42];
    const float* lns_b = (const float*)d_in[43];
    const float* lne_g = (const float*)d_in[44];
    const float* lne_b = (const float*)d_in[45];
    const float* lnf_g = (const float*)d_in[46];
    const float* lnf_b = (const float*)d_in[47];
    const float* wq = (const float*)d_in[48];
    const float* wk = (const float*)d_in[49];
    const float* wv = (const float*)d_in[50];
    const float* f_w1 = (const float*)d_in[51];
    const float* f_b1 = (const float*)d_in[52];
    const float* f_w2 = (const float*)d_in[53];
    const float* f_b2 = (const float*)d_in[54];

    // workspace layout (~16.7 MB)
    float* ws   = (float*)d_ws;
    float* hr   = ws;
    float* hr2  = hr   + T_ * DH_;
    float* qkva = hr2  + T_ * DH_;
    float* qkvb = qkva + T_ * 192;
    float* atta = qkvb + T_ * 192;
    float* attb = atta + T_ * DM_;
    float* x1f  = attb + T_ * DM_;
    float* x2f  = x1f  + T_ * DM_;
    float* x3f  = x2f  + T_ * DM_;
    unsigned short* Wfrag = (unsigned short*)(x3f + T_ * DM_);      // meta frags
    unsigned short* Wsm   = Wfrag + 3 * WFRAG_G;                     // small frags
    float* hr_r = attb;               // stage-1 hr (consumed before attb reuse)

    auto U = [&](int i) { return (const unsigned short*)(Wsm + (size_t)i * 4096); };

    // one-time weight permutes
    k_wconv<<<(3 * NG_ * NC_ * 64 + 255) / 256, 256, 0, stream>>>(
        mr_w2, mr_b2, ms0_w2, ms0_b2, ms1_w2, ms1_b2, Wfrag);
    k_wconv2<<<dim3(8, 19), 256, 0, stream>>>(
        swr_wg, swr_wo, sws_wg, sws_wo, swe_wg, swe_wo, wq, wk, wv, f_w1, f_w2,
        g2_W1, g2_W2, gr_W1, gr_W2, gs0_W1, gs0_W2, gs1_W1, gs1_W2, ge_W1, ge_W2,
        Wsm);

    // meta hiddens
    k_hr3<<<dim3(510, 3), 256, 0, stream>>>(c_x, mr_w1, mr_b1, ms0_w1, ms0_b1,
                                            ms1_w1, ms1_b1, hr_r, hr, hr2);

    // ---- stage 1: retnet retention ----
    k_meta_gemm2<<<dim3(64, 3, 1), 256, 0, stream>>>(
        hr_r, hr_r, x, Wfrag, Wfrag, qkva, qkva);
    k_retnet<<<B_ * N_, 256, 0, stream>>>(qkva, Dm, atta);
    k_gsl5<<<64, 256, 0, stream>>>(atta, x, U(21), U(0), U(1),
                                   swr_bg, swr_bo, lnr_g, lnr_b, x1f);

    // ---- stage 2: spatial ----
    k_meta_gemm2<<<dim3(64, 3, 2), 256, 0, stream>>>(
        hr, hr2, x1f, Wfrag + WFRAG_G, Wfrag + 2 * WFRAG_G, qkva, qkvb);
    k_spatial4<<<dim3(B_ * P_, H_, 8), 256, 0, stream>>>(qkva, qkvb, Tm, Am, atta, attb);
    k_spatial_fuse5<<<64, 256, 0, stream>>>(atta, attb, x1f,
                                            U(29), U(37), U(17), U(18), U(19), U(20),
                                            U(2), U(3), sws_bg, sws_bo, lns_g, lns_b, x2f);

    // ---- stage 3: temporal enc-dec ----
    k_qkvproj5<<<64, 256, 0, stream>>>(x2f, enc, U(6), U(7), U(8), qkva);
    k_temporal<<<B_ * N_, 256, 0, stream>>>(qkva, atta);
    k_gsl5<<<64, 256, 0, stream>>>(atta, x2f, U(45), U(4), U(5),
                                   swe_bg, swe_bo, lne_g, lne_b, x3f);

    // ---- stage 4: FFN ----
    k_ffn5<<<64, 256, 0, stream>>>(x3f, U(9), f_b1, U(13), f_b2, lnf_g, lnf_b,
                                   (float*)d_out);
}